// Round 1
// baseline (15344.830 us; speedup 1.0000x reference)
//
#include <hip/hip_runtime.h>
#include <math.h>

// ---------------------------------------------------------------------------
// CurvePredictor: encoder MLP -> 2-layer LSTM (T=256) -> decoder MLP
// Fully fused persistent kernel: 128 blocks x 1024 threads, each block owns
// 16 batch rows across all timesteps. bf16 MFMA (16x16x32) for every matmul.
// Weights converted to bf16 (gate-interleaved) by a prep kernel into d_ws.
// ---------------------------------------------------------------------------

typedef __attribute__((ext_vector_type(8))) short s8v;   // 8 x bf16 (4 VGPRs)
typedef __attribute__((ext_vector_type(4))) float f4v;   // 4 x f32 acc

__device__ __forceinline__ f4v mfma16(s8v a, s8v b, f4v c){
  return __builtin_amdgcn_mfma_f32_16x16x32_bf16(a, b, c, 0, 0, 0);
}

__device__ __forceinline__ short f2bf(float f){          // RNE f32 -> bf16
  unsigned u = __float_as_uint(f);
  u = u + 0x7FFFu + ((u >> 16) & 1u);
  return (short)(u >> 16);
}

__device__ __forceinline__ float wred(float v){          // 64-lane sum
  #pragma unroll
  for (int o = 32; o; o >>= 1) v += __shfl_xor(v, o);
  return v;
}

__device__ __forceinline__ float sigm(float x){ return 1.0f / (1.0f + __expf(-x)); }
__device__ __forceinline__ float tnh(float x){
  x = fminf(15.0f, fmaxf(-15.0f, x));
  float e = __expf(2.0f * x);
  return (e - 1.0f) / (e + 1.0f);
}
__device__ __forceinline__ float gelu_exact(float v){
  return 0.5f * v * (1.0f + erff(v * 0.70710678118654752440f));
}

// ws layout (shorts):
//   [0,       262144)  Wih0 bf16, gate-interleaved: row' = hid*4 + gate
//   [262144,  524288)  Whh0 bf16, interleaved
//   [524288,  786432)  Wih1 bf16, interleaved
//   [786432, 1048576)  Whh1 bf16, interleaved
//   [1048576,1081344)  W3  bf16 row-major [128][256]
//   [1081344,1083392)  W4  bf16 zero-padded to [16][128]
// then fp32 bias1[1024] (= bih1+bhh1) at byte offset 2166784.

__global__ void prep_kernel(
    const float* __restrict__ Wih0, const float* __restrict__ Whh0,
    const float* __restrict__ Wih1, const float* __restrict__ Whh1,
    const float* __restrict__ W3,   const float* __restrict__ W4,
    const float* __restrict__ bih1, const float* __restrict__ bhh1,
    short* __restrict__ wsb, float* __restrict__ bias1)
{
  const int i = blockIdx.x * 256 + threadIdx.x;
  if (i < 1024) bias1[i] = bih1[i] + bhh1[i];
  if (i >= 1083392) return;
  float v;
  if (i < 1048576){
    const int seg  = i >> 18;        // which 1024x256 matrix
    const int j    = i & 262143;
    const int rowp = j >> 8;         // interleaved row: hid*4 + gate
    const int col  = j & 255;
    const int g    = rowp & 3;
    const int hid  = rowp >> 2;
    const int src  = (g * 256 + hid) * 256 + col;
    const float* m = (seg == 0) ? Wih0 : (seg == 1) ? Whh0 : (seg == 2) ? Wih1 : Whh1;
    v = m[src];
  } else if (i < 1081344){
    v = W3[i - 1048576];
  } else {
    const int j = i - 1081344;
    const int r = j >> 7, c = j & 127;
    v = (r < 2) ? W4[r * 128 + c] : 0.0f;   // zero-pad rows 2..15
  }
  wsb[i] = f2bf(v);
}

// 4 gate tiles (16 cols each) accumulated over K=256 from one LDS h-buffer.
// pw is the per-lane weight base (interleaved layout, gate stride = 32 s8v).
__device__ __forceinline__ void gemm4(const short* ldsrow, const s8v* pw, int q, f4v* acc){
  const s8v* ap = (const s8v*)ldsrow;
  #pragma unroll
  for (int kk = 0; kk < 8; kk++){
    s8v a = ap[kk * 4 + q];
    #pragma unroll
    for (int g = 0; g < 4; g++)
      acc[g] = mfma16(a, pw[g * 32 + kk * 4 + q], acc[g]);
  }
}

__global__ __launch_bounds__(1024, 1) void curve_main(
    const float* __restrict__ x,
    const float* __restrict__ W1, const float* __restrict__ b1,
    const float* __restrict__ g1, const float* __restrict__ be1,
    const float* __restrict__ W2, const float* __restrict__ b2,
    const float* __restrict__ g2, const float* __restrict__ be2,
    const float* __restrict__ bih0, const float* __restrict__ bhh0,
    const float* __restrict__ b3, const float* __restrict__ b4,
    const short* __restrict__ wsb, const float* __restrict__ bias1,
    float* __restrict__ out)
{
  const int tid   = threadIdx.x;
  const int w     = tid >> 6;      // wave 0..15  <-> hidden slice / encoder row
  const int lane  = tid & 63;
  const int q     = lane >> 4;     // quad 0..3
  const int m16   = lane & 15;
  const int brow0 = blockIdx.x * 16;

  // stride 264 shorts = 528B = 33*16 -> 16B-aligned rows, uniform bank spread
  __shared__ __align__(16) short h0_lds[16 * 264];
  __shared__ __align__(16) short h1_lds[16 * 264];
  __shared__ __align__(16) short d_lds [16 * 136];

  // ----------------- encoder: wave w computes batch row brow0+w -------------
  {
    const int r = brow0 + w;
    float xv[5];
    #pragma unroll
    for (int k = 0; k < 5; k++) xv[k] = x[r * 5 + k];
    float a0 = b1[lane], a1 = b1[lane + 64];
    #pragma unroll
    for (int k = 0; k < 5; k++){
      a0 += xv[k] * W1[lane * 5 + k];
      a1 += xv[k] * W1[(lane + 64) * 5 + k];
    }
    a0 = gelu_exact(a0); a1 = gelu_exact(a1);
    float mean = wred(a0 + a1) * (1.0f / 128.0f);
    float d0 = a0 - mean, d1 = a1 - mean;
    float inv = rsqrtf(wred(d0 * d0 + d1 * d1) * (1.0f / 128.0f) + 1e-5f);
    float y0 = d0 * inv * g1[lane]      + be1[lane];
    float y1 = d1 * inv * g1[lane + 64] + be1[lane + 64];

    float acc2[4];
    #pragma unroll
    for (int u = 0; u < 4; u++) acc2[u] = b2[lane + 64 * u];
    for (int k = 0; k < 64; k++){
      float v0 = __shfl(y0, k);
      float v1 = __shfl(y1, k);
      #pragma unroll
      for (int u = 0; u < 4; u++){
        const float* wr = W2 + (lane + 64 * u) * 128;
        acc2[u] += v0 * wr[k] + v1 * wr[k + 64];
      }
    }
    #pragma unroll
    for (int u = 0; u < 4; u++) acc2[u] = gelu_exact(acc2[u]);
    float s = acc2[0] + acc2[1] + acc2[2] + acc2[3];
    mean = wred(s) * (1.0f / 256.0f);
    float vv = 0.0f;
    #pragma unroll
    for (int u = 0; u < 4; u++){ float d = acc2[u] - mean; vv += d * d; }
    inv = rsqrtf(wred(vv) * (1.0f / 256.0f) + 1e-5f);
    #pragma unroll
    for (int u = 0; u < 4; u++){
      int c = lane + 64 * u;
      float e = (acc2[u] - mean) * inv * g2[c] + be2[c];
      h0_lds[w * 264 + c] = f2bf(e);      // enc staged as A-operand bf16
    }
  }
  __syncthreads();

  const int hidc = w * 16 + m16;          // this lane's hidden column

  // ------- xp0 = enc @ Wih0^T + bih0 + bhh0, kept entirely in registers ----
  f4v xp[4];
  {
    #pragma unroll
    for (int g = 0; g < 4; g++){
      int n = g * 256 + hidc;
      float bi = bih0[n] + bhh0[n];
      f4v t = {bi, bi, bi, bi};
      xp[g] = t;
    }
    const s8v* pw = (const s8v*)wsb + hidc * 128;   // Wih0 interleaved
    gemm4(h0_lds + m16 * 264, pw, q, xp);
  }
  __syncthreads();
  for (int i = tid; i < 16 * 264; i += 1024){ h0_lds[i] = 0; h1_lds[i] = 0; }
  __syncthreads();

  const s8v* pwh0 = (const s8v*)(wsb +  262144) + hidc * 128;
  const s8v* pwi1 = (const s8v*)(wsb +  524288) + hidc * 128;
  const s8v* pwh1 = (const s8v*)(wsb +  786432) + hidc * 128;
  const s8v* pw3  = (const s8v*)(wsb + 1048576) + hidc * 32;   // valid for w<8
  const s8v* pw4  = (const s8v*)(wsb + 1081344) + m16 * 16;
  float bs1[4];
  #pragma unroll
  for (int g = 0; g < 4; g++) bs1[g] = bias1[g * 256 + hidc];
  const float b3c = (w < 8)   ? b3[hidc] : 0.0f;
  const float b4v = (m16 < 2) ? b4[m16]  : 0.0f;
  float c0[4] = {0, 0, 0, 0}, c1[4] = {0, 0, 0, 0};

  // --------------------------- recurrence over T ---------------------------
  for (int t = 0; t < 256; t++){
    // layer 0: gates = xp0 + h0 @ Whh0^T
    f4v acc[4] = {xp[0], xp[1], xp[2], xp[3]};
    gemm4(h0_lds + m16 * 264, pwh0, q, acc);
    float h0v[4];
    #pragma unroll
    for (int r = 0; r < 4; r++){
      float ig = sigm(acc[0][r]);
      float fg = sigm(acc[1][r]);
      float gg = tnh (acc[2][r]);
      float og = sigm(acc[3][r]);
      c0[r]  = fg * c0[r] + ig * gg;
      h0v[r] = og * tnh(c0[r]);
    }
    __syncthreads();                       // all waves done reading old h0
    #pragma unroll
    for (int r = 0; r < 4; r++) h0_lds[(q * 4 + r) * 264 + hidc] = f2bf(h0v[r]);
    __syncthreads();                       // new h0 visible

    // layer 1: gates = bias1 + h0 @ Wih1^T + h1_old @ Whh1^T
    f4v acc1[4];
    #pragma unroll
    for (int g = 0; g < 4; g++){ f4v tv = {bs1[g], bs1[g], bs1[g], bs1[g]}; acc1[g] = tv; }
    gemm4(h0_lds + m16 * 264, pwi1, q, acc1);
    gemm4(h1_lds + m16 * 264, pwh1, q, acc1);
    float h1v[4];
    #pragma unroll
    for (int r = 0; r < 4; r++){
      float ig = sigm(acc1[0][r]);
      float fg = sigm(acc1[1][r]);
      float gg = tnh (acc1[2][r]);
      float og = sigm(acc1[3][r]);
      c1[r]  = fg * c1[r] + ig * gg;
      h1v[r] = og * tnh(c1[r]);
    }
    __syncthreads();                       // all waves done reading old h1
    #pragma unroll
    for (int r = 0; r < 4; r++) h1_lds[(q * 4 + r) * 264 + hidc] = f2bf(h1v[r]);
    __syncthreads();                       // new h1 visible

    // decoder stage 1: d = gelu(h1 @ W3^T + b3)   (waves 0..7, 128 cols)
    if (w < 8){
      f4v ad = {b3c, b3c, b3c, b3c};
      const s8v* ap = (const s8v*)(h1_lds + m16 * 264);
      #pragma unroll
      for (int kk = 0; kk < 8; kk++) ad = mfma16(ap[kk * 4 + q], pw3[kk * 4 + q], ad);
      #pragma unroll
      for (int r = 0; r < 4; r++) d_lds[(q * 4 + r) * 136 + hidc] = f2bf(gelu_exact(ad[r]));
    }
    __syncthreads();                       // d visible

    // decoder stage 2: out = d @ W4^T + b4   (wave 0, N padded to 16)
    if (w == 0){
      f4v ao = {0.0f, 0.0f, 0.0f, 0.0f};
      const s8v* ap = (const s8v*)(d_lds + m16 * 136);
      #pragma unroll
      for (int kk = 0; kk < 4; kk++) ao = mfma16(ap[kk * 4 + q], pw4[kk * 4 + q], ao);
      if (m16 < 2){
        #pragma unroll
        for (int r = 0; r < 4; r++)
          out[((brow0 + q * 4 + r) * 256 + t) * 2 + m16] = ao[r] + b4v;
      }
    }
  }
}

extern "C" void kernel_launch(void* const* d_in, const int* in_sizes, int n_in,
                              void* d_out, int out_size, void* d_ws, size_t ws_size,
                              hipStream_t stream)
{
  const float* x    = (const float*)d_in[0];
  const float* W1   = (const float*)d_in[1];
  const float* b1   = (const float*)d_in[2];
  const float* g1   = (const float*)d_in[3];
  const float* be1  = (const float*)d_in[4];
  const float* W2   = (const float*)d_in[5];
  const float* b2   = (const float*)d_in[6];
  const float* g2   = (const float*)d_in[7];
  const float* be2  = (const float*)d_in[8];
  const float* Wih0 = (const float*)d_in[9];
  const float* Whh0 = (const float*)d_in[10];
  const float* bih0 = (const float*)d_in[11];
  const float* bhh0 = (const float*)d_in[12];
  const float* Wih1 = (const float*)d_in[13];
  const float* Whh1 = (const float*)d_in[14];
  const float* bih1 = (const float*)d_in[15];
  const float* bhh1 = (const float*)d_in[16];
  const float* W3   = (const float*)d_in[17];
  const float* b3   = (const float*)d_in[18];
  const float* W4   = (const float*)d_in[19];
  const float* b4   = (const float*)d_in[20];

  short* wsb   = (short*)d_ws;
  float* bias1 = (float*)((char*)d_ws + 2166784);

  prep_kernel<<<4232, 256, 0, stream>>>(Wih0, Whh0, Wih1, Whh1, W3, W4,
                                        bih1, bhh1, wsb, bias1);
  curve_main<<<128, 1024, 0, stream>>>(x, W1, b1, g1, be1, W2, b2, g2, be2,
                                       bih0, bhh0, b3, b4, wsb, bias1,
                                       (float*)d_out);
}